// Round 1
// baseline (817.224 us; speedup 1.0000x reference)
//
#include <hip/hip_runtime.h>
#include <hip/hip_bf16.h>
#include <math.h>

#define EMB 64

// ---------------- CSR build ----------------

__global__ void zero_counts(int* ucur, int* icur, int nu, int ni) {
    int i = blockIdx.x * blockDim.x + threadIdx.x;
    if (i < nu) ucur[i] = 0;
    else if (i < nu + ni) icur[i - nu] = 0;
}

__global__ void hist_rows(const int* __restrict__ urows, int eu,
                          const int* __restrict__ irows, int ei,
                          int* ucur, int* icur) {
    int i = blockIdx.x * blockDim.x + threadIdx.x;
    if (i < eu) atomicAdd(&ucur[urows[i]], 1);
    else if (i < eu + ei) atomicAdd(&icur[irows[i - eu]], 1);
}

// inclusive scan of v across a 1024-thread block; wsum is 16-int shared
__device__ __forceinline__ int block_scan_1024(int v, int* wsum) {
    int tid = threadIdx.x, lane = tid & 63, wid = tid >> 6;
    int s = v;
#pragma unroll
    for (int d = 1; d < 64; d <<= 1) {
        int t = __shfl_up(s, d);
        if (lane >= d) s += t;
    }
    if (lane == 63) wsum[wid] = s;
    __syncthreads();
    if (tid < 16) {
        int ws = wsum[tid];
#pragma unroll
        for (int d = 1; d < 16; d <<= 1) {
            int t = __shfl_up(ws, d);
            if (tid >= d) ws += t;
        }
        wsum[tid] = ws;
    }
    __syncthreads();
    int wpref = (wid > 0) ? wsum[wid - 1] : 0;
    return wpref + s;
}

// Phase A: per-block local inclusive scan of counts -> off[i+1], blocksums
__global__ void scanA(const int* __restrict__ ucnt, int nu, int* uoff, int* ubsum, int nbu,
                      const int* __restrict__ icnt, int ni, int* ioff, int* ibsum) {
    __shared__ int wsum[16];
    const int* cnt; int n; int* off; int* bsum; int b;
    if ((int)blockIdx.x < nbu) { cnt = ucnt; n = nu; off = uoff; bsum = ubsum; b = blockIdx.x; }
    else { cnt = icnt; n = ni; off = ioff; bsum = ibsum; b = blockIdx.x - nbu; }
    int tid = threadIdx.x;
    int i = b * 1024 + tid;
    int v = (i < n) ? cnt[i] : 0;
    int incl = block_scan_1024(v, wsum);
    if (i < n) off[i + 1] = incl;
    if (tid == 1023) bsum[b] = wsum[15];
}

// Phase B: exclusive scan of blocksums in place (nb <= 1024), grid = 2 blocks
__global__ void scanB(int* ubsum, int nbu, int* ibsum, int nbi) {
    __shared__ int wsum[16];
    int* bsum; int nb;
    if (blockIdx.x == 0) { bsum = ubsum; nb = nbu; } else { bsum = ibsum; nb = nbi; }
    int tid = threadIdx.x;
    int v = (tid < nb) ? bsum[tid] : 0;
    int incl = block_scan_1024(v, wsum);
    if (tid < nb) bsum[tid] = incl - v;
}

// Phase C: finalize offsets (+ block prefix), init cursors
__global__ void scanC(int* uoff, int* ucur, const int* __restrict__ ubpref, int nu,
                      int* ioff, int* icur, const int* __restrict__ ibpref, int ni) {
    int i = blockIdx.x * blockDim.x + threadIdx.x;
    int* off; int* cur; const int* bp; int n; int j;
    if (i <= nu) { off = uoff; cur = ucur; bp = ubpref; n = nu; j = i; }
    else {
        j = i - (nu + 1);
        if (j > ni) return;
        off = ioff; cur = icur; bp = ibpref; n = ni;
    }
    int val;
    if (j == 0) val = 0;
    else val = off[j] + bp[(j - 1) >> 10];
    off[j] = val;
    if (j < n) cur[j] = val;
}

__global__ void scatter_edges(const int* __restrict__ urows, const int* __restrict__ ucols,
                              const float* __restrict__ uvals, int eu, int* ucur,
                              int* __restrict__ ccolU, float* __restrict__ cvalU,
                              const int* __restrict__ irows, const int* __restrict__ icols,
                              const float* __restrict__ ivals, int ei, int* icur,
                              int* __restrict__ ccolI, float* __restrict__ cvalI) {
    int i = blockIdx.x * blockDim.x + threadIdx.x;
    if (i < eu) {
        int slot = atomicAdd(&ucur[urows[i]], 1);
        ccolU[slot] = ucols[i];
        cvalU[slot] = uvals[i];
    } else if (i < eu + ei) {
        int k = i - eu;
        int slot = atomicAdd(&icur[irows[k]], 1);
        ccolI[slot] = icols[k];
        cvalI[slot] = ivals[k];
    }
}

// ---------------- SPMM: one wave per row, lane = feature ----------------

__global__ __launch_bounds__(256) void spmm_csr(
    const int* __restrict__ uoff, const int* __restrict__ ccolU, const float* __restrict__ cvalU,
    const float* __restrict__ xu, float* __restrict__ yu, int nu, int sbu,
    const int* __restrict__ ioff, const int* __restrict__ ccolI, const float* __restrict__ cvalI,
    const float* __restrict__ xi, float* __restrict__ yi, int ni) {
    int lane = threadIdx.x & 63, wid = threadIdx.x >> 6;
    const int* off; const int* ccol; const float* cval; const float* x; float* y; int n; int row;
    if ((int)blockIdx.x < sbu) {
        off = uoff; ccol = ccolU; cval = cvalU; x = xu; y = yu; n = nu;
        row = blockIdx.x * 4 + wid;
    } else {
        off = ioff; ccol = ccolI; cval = cvalI; x = xi; y = yi; n = ni;
        row = (blockIdx.x - sbu) * 4 + wid;
    }
    if (row >= n) return;
    int s = off[row], e = off[row + 1];
    float acc = 0.f;
    int p = s;
    for (; p + 1 < e; p += 2) {
        int c0 = ccol[p], c1 = ccol[p + 1];
        float v0 = cval[p], v1 = cval[p + 1];
        acc += v0 * x[(size_t)c0 * EMB + lane];
        acc += v1 * x[(size_t)c1 * EMB + lane];
    }
    if (p < e) acc += cval[p] * x[(size_t)ccol[p] * EMB + lane];
    y[(size_t)row * EMB + lane] = acc;
}

// ---------------- dense (x @ W^T + b) + leaky_relu + L2 norm ----------------

__global__ __launch_bounds__(256) void dense_lrelu_norm(
    const float* __restrict__ xu, const float* __restrict__ Wu, const float* __restrict__ bu,
    float* __restrict__ yu, int nu, int gbu,
    const float* __restrict__ xi, const float* __restrict__ Wi, const float* __restrict__ bi,
    float* __restrict__ yi, int ni) {
    int lane = threadIdx.x & 63, wid = threadIdx.x >> 6;
    const float* x; const float* W; const float* bv; float* y; int n; int b; int nblocks;
    if ((int)blockIdx.x < gbu) {
        x = xu; W = Wu; bv = bu; y = yu; n = nu; b = blockIdx.x; nblocks = gbu;
    } else {
        x = xi; W = Wi; bv = bi; y = yi; n = ni; b = blockIdx.x - gbu; nblocks = gridDim.x - gbu;
    }
    float w[EMB];
#pragma unroll
    for (int k = 0; k < EMB; ++k) w[k] = W[lane * EMB + k];
    float bias = bv[lane];
    int stride = nblocks * 4;
    for (int row = b * 4 + wid; row < n; row += stride) {
        float xv = x[(size_t)row * EMB + lane];
        float acc = bias;
#pragma unroll
        for (int k = 0; k < EMB; ++k) acc = fmaf(w[k], __shfl(xv, k), acc);
        acc = (acc > 0.f) ? acc : 0.01f * acc;
        float ss = acc * acc;
#pragma unroll
        for (int d = 32; d >= 1; d >>= 1) ss += __shfl_xor(ss, d);
        float nrm = sqrtf(ss);
        float scl = 1.0f / fmaxf(nrm, 1e-12f);
        y[(size_t)row * EMB + lane] = acc * scl;
    }
}

// ---------------- launch ----------------

extern "C" void kernel_launch(void* const* d_in, const int* in_sizes, int n_in,
                              void* d_out, int out_size, void* d_ws, size_t ws_size,
                              hipStream_t stream) {
    const float* user_emb = (const float*)d_in[0];
    const float* item_emb = (const float*)d_in[1];
    const float* Wu0 = (const float*)d_in[2];
    const float* bu0 = (const float*)d_in[3];
    const float* Wu1 = (const float*)d_in[4];
    const float* bu1 = (const float*)d_in[5];
    const float* Wi0 = (const float*)d_in[6];
    const float* bi0 = (const float*)d_in[7];
    const float* Wi1 = (const float*)d_in[8];
    const float* bi1 = (const float*)d_in[9];
    const int*   u_rows = (const int*)d_in[10];
    const int*   u_cols = (const int*)d_in[11];
    const float* u_vals = (const float*)d_in[12];
    const int*   i_rows = (const int*)d_in[13];
    const int*   i_cols = (const int*)d_in[14];
    const float* i_vals = (const float*)d_in[15];

    const int nu = in_sizes[0] / EMB;
    const int ni = in_sizes[1] / EMB;
    const int eu = in_sizes[10];
    const int ei = in_sizes[13];

    float* out_u = (float*)d_out;
    float* out_i = out_u + (size_t)nu * EMB;

    // workspace carve (256B aligned)
    size_t o = 0;
    char* wsb = (char*)d_ws;
    auto carve = [&](size_t bytes) -> void* {
        void* p = wsb + o;
        o += (bytes + 255) & ~(size_t)255;
        return p;
    };
    float* atmp_u = (float*)carve((size_t)nu * EMB * 4);
    float* atmp_i = (float*)carve((size_t)ni * EMB * 4);
    int*   uoff  = (int*)carve((size_t)(nu + 1) * 4);
    int*   ucur  = (int*)carve((size_t)nu * 4);
    int*   ioff  = (int*)carve((size_t)(ni + 1) * 4);
    int*   icur  = (int*)carve((size_t)ni * 4);
    int*   ubsum = (int*)carve(1024 * 4);
    int*   ibsum = (int*)carve(1024 * 4);
    int*   ccolU = (int*)carve((size_t)eu * 4);
    float* cvalU = (float*)carve((size_t)eu * 4);
    int*   ccolI = (int*)carve((size_t)ei * 4);
    float* cvalI = (float*)carve((size_t)ei * 4);
    (void)ws_size;

    // ---- CSR build (edges are layer-invariant: build once per call) ----
    {
        int tot = nu + ni;
        zero_counts<<<(tot + 255) / 256, 256, 0, stream>>>(ucur, icur, nu, ni);
        int te = eu + ei;
        hist_rows<<<(te + 255) / 256, 256, 0, stream>>>(u_rows, eu, i_rows, ei, ucur, icur);
        int nbu = (nu + 1023) / 1024, nbi = (ni + 1023) / 1024;
        scanA<<<nbu + nbi, 1024, 0, stream>>>(ucur, nu, uoff, ubsum, nbu, icur, ni, ioff, ibsum);
        scanB<<<2, 1024, 0, stream>>>(ubsum, nbu, ibsum, nbi);
        int totoff = (nu + 1) + (ni + 1);
        scanC<<<(totoff + 255) / 256, 256, 0, stream>>>(uoff, ucur, ubsum, nu, ioff, icur, ibsum, ni);
        scatter_edges<<<(te + 255) / 256, 256, 0, stream>>>(
            u_rows, u_cols, u_vals, eu, ucur, ccolU, cvalU,
            i_rows, i_cols, i_vals, ei, icur, ccolI, cvalI);
    }

    // ---- 2 GCN layers ----
    int sbu = (nu + 3) / 4, sbi = (ni + 3) / 4;
    const int GBU = 1024, GBI = 512;
    for (int l = 0; l < 2; ++l) {
        const float* xu = l ? out_u : user_emb;
        const float* xi = l ? out_i : item_emb;
        spmm_csr<<<sbu + sbi, 256, 0, stream>>>(uoff, ccolU, cvalU, xu, atmp_u, nu, sbu,
                                                ioff, ccolI, cvalI, xi, atmp_i, ni);
        dense_lrelu_norm<<<GBU + GBI, 256, 0, stream>>>(
            atmp_u, l ? Wu1 : Wu0, l ? bu1 : bu0, out_u, nu, GBU,
            atmp_i, l ? Wi1 : Wi0, l ? bi1 : bi0, out_i, ni);
    }
}